// Round 11
// baseline (238.713 us; speedup 1.0000x reference)
//
#include <hip/hip_runtime.h>
#include <math.h>

#define TPB 256
#define EPT 16      // elements per thread
#define NN  4096    // row length (fixed by problem)
#define KSEL 410    // K = round(4096 * 0.1)
#define CAP 1024    // candidate list capacity (expected max bin ~95)
#define ROWS 8      // rows per block (pipeline depth amortizes fill)

typedef float floatx4 __attribute__((ext_vector_type(4)));

// Monotonic float->uint key: larger float => larger unsigned key.
__device__ __forceinline__ unsigned sortkey(float f) {
    unsigned u = __float_as_uint(f);
    unsigned m = (unsigned)(((int)u) >> 31);     // 0x00000000 or 0xFFFFFFFF
    return u ^ (m | 0x80000000u);
}

// Async global->LDS DMA, 16B per lane. gsrc is PER-LANE; lds dest is wave-uniform
// base, HW writes base + lane*16 [m104/m108]. Void side-effecting intrinsic: the
// compiler preserves issue position (cannot sink to first use) [m97 pattern].
__device__ __forceinline__ void dma16(const float* gsrc, float* lds) {
    __builtin_amdgcn_global_load_lds(
        (__attribute__((address_space(1))) void*)(void*)gsrc,
        (__attribute__((address_space(3))) void*)(void*)lds,
        16, 0, 0);
}

// Raw workgroup barrier: drain MY LDS ops, then s_barrier. Does NOT drain vmcnt,
// so in-flight DMA survives the selection phase (T4: never drain vmcnt in-loop).
__device__ __forceinline__ void barsync() {
    asm volatile("s_waitcnt lgkmcnt(0)" ::: "memory");
    __builtin_amdgcn_s_barrier();
}

// Counted vmem wait (rule #18: memory clobber + sched_barrier fence consumers).
#define VMWAIT(N) do { \
    asm volatile("s_waitcnt vmcnt(" #N ")" ::: "memory"); \
    __builtin_amdgcn_sched_barrier(0); \
} while (0)

// Stage row rw's x and g into stage buffer b (wave-private 8KB region / wave).
// Thread t=(w,lane) will consume elements q*1024 + t*4 + (0..3).
#define ISSUE_DMA(rw, b) do { \
    const float* xr_ = x + (size_t)(rw) * NN; \
    const float* gr_ = g + (size_t)(rw) * NN; \
    float* sb_ = &stage[b][w * 2048]; \
    _Pragma("unroll") \
    for (int q_ = 0; q_ < 4; ++q_) { \
        dma16(xr_ + q_ * 1024 + w * 256 + lane * 4, sb_ + q_ * 256); \
        dma16(gr_ + q_ * 1024 + w * 256 + lane * 4, sb_ + 1024 + q_ * 256); \
    } \
} while (0)

template <bool USE_WS>
__global__ __launch_bounds__(TPB)
void skw_main(const float* __restrict__ x, const float* __restrict__ g,
              float* __restrict__ out, float* __restrict__ rowH,
              float* __restrict__ entAcc, float invB, int nrows)
{
    const int t    = threadIdx.x;
    const int w    = t >> 6;          // wave id 0..3
    const int lane = t & 63;

    __shared__ float    stage[2][8192];  // 2 x 32KB: double-buffered row staging
    __shared__ unsigned hist0[256][9];   // bin histogram: 8 slots + 1 pad (stride 9)
    __shared__ unsigned wtot[4];
    __shared__ unsigned wtA[4], wtB[4];
    __shared__ float    fred[8];
    __shared__ unsigned sh_digit, sh_above, sh_cnt, sh_thr, sh_take;

    unsigned* list = &hist0[0][0];       // aliases hist0; only written after B4 (hist0 dead)

    const int r0 = blockIdx.x * ROWS;
    if (r0 >= nrows) return;
    const int rend = (r0 + ROWS < nrows) ? (r0 + ROWS) : nrows;

    int cur = 0;
    ISSUE_DMA(r0, 0);                    // pipeline fill

#pragma unroll 1
    for (int row = r0; row < rend; ++row) {
        // Wait for THIS row's DMA. Queue: [DMA(row) x8, (rowH), nt-stores x8] ->
        // vmcnt(8) retires the 8 DMAs (+rowH on wave 0), leaves stores pending.
        if (row == r0) { VMWAIT(0); } else { VMWAIT(8); }

        // Issue NEXT row's DMA immediately: streams under keys + whole selection.
        // WAR-safe: buffer cur^1 was last ds_read two barriers ago (same wave only).
        if (row + 1 < rend) ISSUE_DMA(row + 1, cur ^ 1);

        const float4* sx = reinterpret_cast<const float4*>(&stage[cur][w * 2048]);

        // ---- keys / bins / entropy partials; exact s = x/10 + g (Markstein) ----
        float    xc[EPT];
        unsigned key[EPT];
        unsigned bp[EPT / 4];
        float sZ = 0.f, sZL = 0.f;
#pragma unroll
        for (int q = 0; q < EPT / 4; ++q) {
            float4 xx = sx[q * 64 + lane];          // staged x chunk q
            float4 gg = sx[256 + q * 64 + lane];    // staged g chunk q (+1024 floats)
            float xa[4] = {xx.x, xx.y, xx.z, xx.w};
            float ga[4] = {gg.x, gg.y, gg.z, gg.w};
            unsigned pk = 0;
#pragma unroll
            for (int jj = 0; jj < 4; ++jj) {
                float xs = xa[jj];
                xc[4 * q + jj] = xs;
                float l = xs * 0.1f;                  // y0 = RN(x * RN(0.1))
                float e = __expf(l);
                sZ  += e;
                sZL = __builtin_fmaf(e, l, sZL);
                // correctly-rounded x/10 (x/10 never lands on an f32 midpoint)
                float q10 = __builtin_fmaf(__builtin_fmaf(-10.0f, l, xs), 0.1f, l);
                float s = q10 + ga[jj];
                key[4 * q + jj] = sortkey(s);
                int b = (int)__builtin_fmaf(s, 16.0f, 64.0f);   // (s+4)*16, monotone
                b = min(max(b, 0), 255);
                pk |= (unsigned)b << (8 * jj);
            }
            bp[q] = pk;
        }

        // ---- entropy reduce (m = 0 safe: |x*0.1| < ~0.6) ----
#pragma unroll
        for (int sft = 32; sft >= 1; sft >>= 1) { sZ += __shfl_xor(sZ, sft); sZL += __shfl_xor(sZL, sft); }
        if (lane == 0) { fred[w] = sZ; fred[4 + w] = sZL; }

        // zero bin histogram (+ counter)
        unsigned* h0 = &hist0[0][0];
#pragma unroll
        for (int i = 0; i < 9; ++i) h0[t + 256 * i] = 0;
        if (t == 0) sh_cnt = 0;
        barsync();                                     // B1

        if (t == 0) {
            float Z = fred[0] + fred[1] + fred[2] + fred[3];
            float L = fred[4] + fred[5] + fred[6] + fred[7];
            float H = __logf(Z) - L / Z;               // H = lnZ - E[l]
            if (USE_WS) rowH[row] = H;
            else atomicAdd(entAcc, H * invB);
        }

        // ---- value-bin histogram (8-way slot split kills serialization) ----
#pragma unroll
        for (int q = 0; q < EPT / 4; ++q) {
            unsigned pk = bp[q];
#pragma unroll
            for (int jj = 0; jj < 4; ++jj)
                atomicAdd(&hist0[(pk >> (8 * jj)) & 255u][lane & 7], 1u);
        }
        barsync();                                     // B2

        // merge slots + inclusive suffix scan (shfl) to find crossing bin B*
        unsigned v = 0;
#pragma unroll
        for (int k = 0; k < 8; ++k) v += hist0[t][k];
#pragma unroll
        for (int sft = 1; sft < 64; sft <<= 1) {
            unsigned tmp = __shfl(v, lane + sft);
            v += (lane + sft < 64) ? tmp : 0u;
        }
        if (lane == 0) wtot[w] = v;
        unsigned vnext = __shfl(v, lane + 1);
        barsync();                                     // B3
        unsigned Kr = KSEL;
        {
            unsigned hi = 0;
#pragma unroll
            for (int c = 0; c < 4; ++c) hi += (c > w) ? wtot[c] : 0u;
            unsigned cum     = v + hi;                          // # keys with bin >= t
            unsigned cumNext = ((lane < 63) ? vnext : 0u) + hi; // # keys with bin >  t
            if (cum >= Kr && cumNext < Kr) { sh_digit = (unsigned)t; sh_above = cumNext; }
        }
        barsync();                                     // B4
        const unsigned Bstar = sh_digit;
        Kr -= sh_above;       // 1-based rank of threshold within bin B*

        // ---- append candidates (bin == B*) to LDS list ----
        unsigned cm = 0;
#pragma unroll
        for (int q = 0; q < EPT / 4; ++q) {
            unsigned pk = bp[q];
#pragma unroll
            for (int jj = 0; jj < 4; ++jj)
                cm |= (((pk >> (8 * jj)) & 255u) == Bstar) ? (1u << (4 * q + jj)) : 0u;
        }
#pragma unroll
        for (int j = 0; j < EPT; ++j) {
            if ((cm >> j) & 1u) {
                unsigned p = atomicAdd(&sh_cnt, 1u);
                if (p < CAP) list[p] = key[j];
            }
        }
        barsync();                                     // B5

        const unsigned M = sh_cnt;                     // count of keys in bin B*
        for (unsigned i = t; i < M; i += TPB) {
            unsigned ki = list[i];
            unsigned gt = 0, eqc = 0;
            for (unsigned j2 = 0; j2 < M; ++j2) {
                unsigned kj = list[j2];                // broadcast read
                gt  += (kj > ki) ? 1u : 0u;
                eqc += (kj == ki) ? 1u : 0u;
            }
            if (gt < Kr && Kr <= gt + eqc) { sh_thr = ki; sh_take = Kr - gt; }
        }
        barsync();                                     // B6
        const unsigned thr    = sh_thr;    // exact K-th largest key overall
        const unsigned KrTake = sh_take;   // # equal keys to accept

        // ===== lowest-index-first ties, column order c = q*1024 + t*4 + jj =====
        unsigned eq[4];
#pragma unroll
        for (int q = 0; q < 4; ++q) {
            unsigned e = 0;
#pragma unroll
            for (int jj = 0; jj < 4; ++jj) e += (key[4 * q + jj] == thr) ? 1u : 0u;
            eq[q] = e;
        }
        unsigned wA = eq[0] | (eq[1] << 16);
        unsigned wB = eq[2] | (eq[3] << 16);
        unsigned sA = wA, sB = wB;
#pragma unroll
        for (int sft = 1; sft < 64; sft <<= 1) {       // inclusive prefix scan in wave
            unsigned ta = __shfl(sA, lane - sft);
            unsigned tb = __shfl(sB, lane - sft);
            if (lane >= sft) { sA += ta; sB += tb; }
        }
        if (lane == 63) { wtA[w] = sA; wtB[w] = sB; }
        barsync();                                     // B7
        unsigned offA = 0, offB = 0, totA = 0, totB = 0;
#pragma unroll
        for (int c = 0; c < 4; ++c) {
            totA += wtA[c]; totB += wtB[c];
            if (c < w) { offA += wtA[c]; offB += wtB[c]; }
        }
        unsigned exA = offA + sA - wA;
        unsigned exB = offB + sB - wB;
        unsigned tot0 = totA & 0xFFFFu, tot1 = totA >> 16, tot2 = totB & 0xFFFFu;
        unsigned baseq[4] = {0u, tot0, tot0 + tot1, tot0 + tot1 + tot2};
        unsigned exq[4]   = {exA & 0xFFFFu, exA >> 16, exB & 0xFFFFu, exB >> 16};

        // ---- write out = x * mask (coalesced full-line nontemporal stores) ----
        floatx4* op = reinterpret_cast<floatx4*>(out + (size_t)row * NN);
#pragma unroll
        for (int q = 0; q < EPT / 4; ++q) {
            unsigned pos = baseq[q] + exq[q];
            float vals[4];
#pragma unroll
            for (int jj = 0; jj < 4; ++jj) {
                int j = 4 * q + jj;
                bool sel;
                if (key[j] > thr)       sel = true;
                else if (key[j] == thr) { sel = (pos < KrTake); ++pos; }
                else                    sel = false;
                vals[jj] = sel ? xc[j] : 0.0f;
            }
            floatx4 o4;
            o4.x = vals[0]; o4.y = vals[1]; o4.z = vals[2]; o4.w = vals[3];
            __builtin_nontemporal_store(o4, &op[(q << 8) + t]);
        }
        cur ^= 1;
    }
}

__global__ void skw_zero(float* p) { *p = 0.0f; }

// Deterministic fixed-order mean of rowH -> out scalar.
__global__ void skw_reduce(const float* __restrict__ rowH, float* __restrict__ outp, int B)
{
    __shared__ float red[256];
    int t = threadIdx.x;
    float s = 0.f;
    for (int i = t; i < B; i += 256) s += rowH[i];
    red[t] = s; __syncthreads();
    for (int st = 128; st > 0; st >>= 1) { if (t < st) red[t] += red[t + st]; __syncthreads(); }
    if (t == 0) *outp = red[0] / (float)B;
}

extern "C" void kernel_launch(void* const* d_in, const int* in_sizes, int n_in,
                              void* d_out, int out_size, void* d_ws, size_t ws_size,
                              hipStream_t stream)
{
    const float* x = (const float*)d_in[0];
    const float* g = (const float*)d_in[1];
    float* out = (float*)d_out;
    const int BN = in_sizes[0];
    const int B  = BN / NN;
    float* entp = out + (size_t)BN;
    const int grid = (B + ROWS - 1) / ROWS;

    if (ws_size >= (size_t)B * sizeof(float)) {
        float* rowH = (float*)d_ws;
        skw_main<true><<<grid, TPB, 0, stream>>>(x, g, out, rowH, nullptr, 0.f, B);
        skw_reduce<<<1, 256, 0, stream>>>(rowH, entp, B);
    } else {
        skw_zero<<<1, 1, 0, stream>>>(entp);
        skw_main<false><<<grid, TPB, 0, stream>>>(x, g, out, nullptr, entp, 1.0f / (float)B, B);
    }
}

// Round 12
// 165.397 us; speedup vs baseline: 1.4433x; 1.4433x over previous
//
#include <hip/hip_runtime.h>
#include <math.h>

#define TPB 256
#define EPT 16      // elements per thread
#define NN  4096    // row length (fixed by problem)
#define KSEL 410    // K = round(4096 * 0.1)
#define CAP 1024    // candidate list capacity (expected max bin ~95)

typedef float floatx4 __attribute__((ext_vector_type(4)));

template <bool USE_WS>
__global__ __launch_bounds__(TPB)
void skw_main(const float* __restrict__ x, const float* __restrict__ g,
              float* __restrict__ out, float* __restrict__ rowH,
              float* __restrict__ entAcc, float invB)
{
    const int row  = blockIdx.x;
    const int t    = threadIdx.x;
    const int w    = t >> 6;          // wave id 0..3
    const int lane = t & 63;
    const size_t rbase = (size_t)row * NN;

    // Thread t, chunk q owns flat elements q*1024 + t*4 + (0..3):
    // every wave instruction touches a contiguous 1 KB => full lines, no RMW.
    float    xv[EPT];                 // x values (for output)
    float    sv[EPT];                 // s = x/10 + g, exact (float domain; no uint key)
    unsigned bp[EPT / 4];             // value-domain bins, byte-packed

    __shared__ unsigned hist0[256][5];   // bin histogram: 4 slots + 1 pad (stride 5)
    __shared__ unsigned wtot[4];
    __shared__ unsigned wtA[4], wtB[4];
    __shared__ float    fred[8];
    __shared__ unsigned sh_digit, sh_above, sh_cnt, sh_take, sh_eq;
    __shared__ float    sh_thr;

    float* list = reinterpret_cast<float*>(&hist0[0][0]);  // alias; written after B4 (5120B >= CAP*4)

    const float4* xp = reinterpret_cast<const float4*>(x + rbase);
    const float4* gp = reinterpret_cast<const float4*>(g + rbase);
    floatx4*      op = reinterpret_cast<floatx4*>(out + rbase);

    // ---- load; entropy partials; exact s = x/10 + g (Markstein div-by-10); value bins ----
    float sZ = 0.f, sZL = 0.f;
#pragma unroll
    for (int q = 0; q < EPT / 4; ++q) {
        float4 xx = xp[(q << 8) + t];
        float4 gg = gp[(q << 8) + t];
        float xa[4] = {xx.x, xx.y, xx.z, xx.w};
        float ga[4] = {gg.x, gg.y, gg.z, gg.w};
        unsigned pk = 0;
#pragma unroll
        for (int jj = 0; jj < 4; ++jj) {
            float xs = xa[jj];
            xv[4 * q + jj] = xs;
            float l = xs * 0.1f;                  // y0 = RN(x * RN(0.1))
            float e = __expf(l);
            sZ  += e;
            sZL = __builtin_fmaf(e, l, sZL);
            // correctly-rounded x/10: q10 = y0 + (x - 10*y0)*0.1 (x/10 never at f32 midpoint)
            float q10 = __builtin_fmaf(__builtin_fmaf(-10.0f, l, xs), 0.1f, l);
            float s = q10 + ga[jj];
            sv[4 * q + jj] = s;
            int b = (int)__builtin_fmaf(s, 16.0f, 64.0f);   // (s+4)*16, monotone in s
            b = min(max(b, 0), 255);
            pk |= (unsigned)b << (8 * jj);
        }
        bp[q] = pk;
    }

    // ---- entropy reduce (m = 0 is safe: |x*0.1| < ~0.6) ----
#pragma unroll
    for (int sft = 32; sft >= 1; sft >>= 1) { sZ += __shfl_xor(sZ, sft); sZL += __shfl_xor(sZL, sft); }
    if (lane == 0) { fred[w] = sZ; fred[4 + w] = sZL; }

    // zero bin histogram (1280 words) + counter
    unsigned* h0 = &hist0[0][0];
#pragma unroll
    for (int i = 0; i < 5; ++i) h0[t + 256 * i] = 0;
    if (t == 0) sh_cnt = 0;
    __syncthreads();                                   // B1

    if (t == 0) {
        float Z = fred[0] + fred[1] + fred[2] + fred[3];
        float L = fred[4] + fred[5] + fred[6] + fred[7];
        float H = __logf(Z) - L / Z;                   // H = lnZ - E[l]
        if (USE_WS) rowH[row] = H;
        else atomicAdd(entAcc, H * invB);
    }

    // ---- value-bin histogram (near-uniform bins; 4-way slot split; 2-way aliasing free) ----
#pragma unroll
    for (int q = 0; q < EPT / 4; ++q) {
        unsigned pk = bp[q];
#pragma unroll
        for (int jj = 0; jj < 4; ++jj)
            atomicAdd(&hist0[(pk >> (8 * jj)) & 255u][lane & 3], 1u);
    }
    __syncthreads();                                   // B2

    // merge slots + inclusive suffix scan (shfl) to find crossing bin B*
    unsigned v = hist0[t][0] + hist0[t][1] + hist0[t][2] + hist0[t][3];
#pragma unroll
    for (int sft = 1; sft < 64; sft <<= 1) {
        unsigned tmp = __shfl(v, lane + sft);
        v += (lane + sft < 64) ? tmp : 0u;
    }
    if (lane == 0) wtot[w] = v;
    unsigned vnext = __shfl(v, lane + 1);
    __syncthreads();                                   // B3
    unsigned Kr = KSEL;
    {
        unsigned hi = 0;
#pragma unroll
        for (int c = 0; c < 4; ++c) hi += (c > w) ? wtot[c] : 0u;
        unsigned cum     = v + hi;                          // # keys with bin >= t
        unsigned cumNext = ((lane < 63) ? vnext : 0u) + hi; // # keys with bin >  t
        if (cum >= Kr && cumNext < Kr) { sh_digit = (unsigned)t; sh_above = cumNext; }
    }
    __syncthreads();                                   // B4
    const unsigned Bstar = sh_digit;
    Kr -= sh_above;       // 1-based rank of threshold within bin B* (from largest)

    // ---- append candidates (bin == B*) to LDS list ----
    unsigned cm = 0;
#pragma unroll
    for (int q = 0; q < EPT / 4; ++q) {
        unsigned pk = bp[q];
#pragma unroll
        for (int jj = 0; jj < 4; ++jj)
            cm |= (((pk >> (8 * jj)) & 255u) == Bstar) ? (1u << (4 * q + jj)) : 0u;
    }
#pragma unroll
    for (int j = 0; j < EPT; ++j) {
        if ((cm >> j) & 1u) {
            unsigned p = atomicAdd(&sh_cnt, 1u);
            if (p < CAP) list[p] = sv[j];
        }
    }
    __syncthreads();                                   // B5

    // ---- exact rank among the ~25-95 candidates (float compares) ----
    const unsigned M = sh_cnt;
    for (unsigned i = t; i < M; i += TPB) {
        float ki = list[i];
        unsigned gt = 0, eqc = 0;
        for (unsigned j2 = 0; j2 < M; ++j2) {
            float kj = list[j2];                       // broadcast read
            gt  += (kj > ki)  ? 1u : 0u;
            eqc += (kj == ki) ? 1u : 0u;
        }
        if (gt < Kr && Kr <= gt + eqc) { sh_thr = ki; sh_take = Kr - gt; sh_eq = eqc; }
    }
    __syncthreads();                                   // B6
    const float    thr    = sh_thr;    // exact K-th largest s overall
    const unsigned KrTake = sh_take;   // # equal-to-thr to accept
    const unsigned EqTot  = sh_eq;     // # equal-to-thr total

    if (KrTake == EqTot) {
        // ---- FAST PATH (unique threshold, the ~always case): sel = s >= thr ----
#pragma unroll
        for (int q = 0; q < EPT / 4; ++q) {
            floatx4 o4;
#pragma unroll
            for (int jj = 0; jj < 4; ++jj) {
                int j = 4 * q + jj;
                o4[jj] = (sv[j] >= thr) ? xv[j] : 0.0f;
            }
            __builtin_nontemporal_store(o4, &op[(q << 8) + t]);
        }
    } else {
        // ===== degenerate ties: lowest-index-first, column order c = q*1024 + t*4 + jj =====
        unsigned eq[4];
#pragma unroll
        for (int q = 0; q < 4; ++q) {
            unsigned e = 0;
#pragma unroll
            for (int jj = 0; jj < 4; ++jj) e += (sv[4 * q + jj] == thr) ? 1u : 0u;
            eq[q] = e;
        }
        unsigned wA = eq[0] | (eq[1] << 16);
        unsigned wB = eq[2] | (eq[3] << 16);
        unsigned sA = wA, sB = wB;
#pragma unroll
        for (int sft = 1; sft < 64; sft <<= 1) {       // inclusive prefix scan within wave
            unsigned ta = __shfl(sA, lane - sft);
            unsigned tb = __shfl(sB, lane - sft);
            if (lane >= sft) { sA += ta; sB += tb; }
        }
        if (lane == 63) { wtA[w] = sA; wtB[w] = sB; }
        __syncthreads();                               // B7 (block-uniform branch: legal)
        unsigned offA = 0, offB = 0, totA = 0, totB = 0;
#pragma unroll
        for (int c = 0; c < 4; ++c) {
            totA += wtA[c]; totB += wtB[c];
            if (c < w) { offA += wtA[c]; offB += wtB[c]; }
        }
        unsigned exA = offA + sA - wA;                 // exclusive prefix, packed halves
        unsigned exB = offB + sB - wB;
        unsigned tot0 = totA & 0xFFFFu, tot1 = totA >> 16, tot2 = totB & 0xFFFFu;
        unsigned baseq[4] = {0u, tot0, tot0 + tot1, tot0 + tot1 + tot2};
        unsigned exq[4]   = {exA & 0xFFFFu, exA >> 16, exB & 0xFFFFu, exB >> 16};

#pragma unroll
        for (int q = 0; q < EPT / 4; ++q) {
            unsigned pos = baseq[q] + exq[q];          // equals before my first elem of this q
            floatx4 o4;
#pragma unroll
            for (int jj = 0; jj < 4; ++jj) {
                int j = 4 * q + jj;
                bool sel;
                if (sv[j] > thr)        sel = true;
                else if (sv[j] == thr)  { sel = (pos < KrTake); ++pos; }
                else                    sel = false;
                o4[jj] = sel ? xv[j] : 0.0f;
            }
            __builtin_nontemporal_store(o4, &op[(q << 8) + t]);
        }
    }
}

__global__ void skw_zero(float* p) { *p = 0.0f; }

// Deterministic fixed-order mean of rowH -> out scalar.
__global__ void skw_reduce(const float* __restrict__ rowH, float* __restrict__ outp, int B)
{
    __shared__ float red[256];
    int t = threadIdx.x;
    float s = 0.f;
    for (int i = t; i < B; i += 256) s += rowH[i];
    red[t] = s; __syncthreads();
    for (int st = 128; st > 0; st >>= 1) { if (t < st) red[t] += red[t + st]; __syncthreads(); }
    if (t == 0) *outp = red[0] / (float)B;
}

extern "C" void kernel_launch(void* const* d_in, const int* in_sizes, int n_in,
                              void* d_out, int out_size, void* d_ws, size_t ws_size,
                              hipStream_t stream)
{
    const float* x = (const float*)d_in[0];
    const float* g = (const float*)d_in[1];
    float* out = (float*)d_out;
    const int BN = in_sizes[0];
    const int B  = BN / NN;
    float* entp = out + (size_t)BN;

    if (ws_size >= (size_t)B * sizeof(float)) {
        float* rowH = (float*)d_ws;
        skw_main<true><<<B, TPB, 0, stream>>>(x, g, out, rowH, nullptr, 0.f);
        skw_reduce<<<1, 256, 0, stream>>>(rowH, entp, B);
    } else {
        skw_zero<<<1, 1, 0, stream>>>(entp);
        skw_main<false><<<B, TPB, 0, stream>>>(x, g, out, nullptr, entp, 1.0f / (float)B);
    }
}

// Round 13
// 165.334 us; speedup vs baseline: 1.4438x; 1.0004x over previous
//
#include <hip/hip_runtime.h>
#include <math.h>

#define TPB 256
#define EPT 16      // elements per thread
#define NN  4096    // row length (fixed by problem)
#define KSEL 410    // K = round(4096 * 0.1)
#define CAP 1024    // candidate list capacity (expected max bin ~95)

typedef float floatx4 __attribute__((ext_vector_type(4)));

template <bool USE_WS>
__global__ __launch_bounds__(TPB, 8)
void skw_main(const float* __restrict__ x, const float* __restrict__ g,
              float* __restrict__ out, float* __restrict__ rowH,
              float* __restrict__ entAcc, float invB)
{
    const int row  = blockIdx.x;
    const int t    = threadIdx.x;
    const int w    = t >> 6;          // wave id 0..3
    const int lane = t & 63;
    const size_t rbase = (size_t)row * NN;

    // Thread t, chunk q owns flat elements q*1024 + t*4 + (0..3).
    // x values stay in registers; s values live in LDS (register-pressure valve:
    // all s accesses are SAME-THREAD, so s_lds needs no barriers at all).
    float    xv[EPT];
    unsigned bp[EPT / 4];             // value-domain bins, byte-packed

    __shared__ float    s_lds[NN];       // 16 KB: s = x/10 + g, block row
    __shared__ unsigned hist0[256][5];   // bin histogram: 4 slots + 1 pad (stride 5)
    __shared__ unsigned wtot[4];
    __shared__ unsigned wtA[4], wtB[4];
    __shared__ float    fred[8];
    __shared__ unsigned sh_digit, sh_above, sh_cnt, sh_take, sh_eq;
    __shared__ float    sh_thr;

    float*   list = reinterpret_cast<float*>(&hist0[0][0]);  // alias; used after B4 (5120B >= CAP*4)
    floatx4* s4   = reinterpret_cast<floatx4*>(s_lds);

    const float4* xp = reinterpret_cast<const float4*>(x + rbase);
    const float4* gp = reinterpret_cast<const float4*>(g + rbase);
    floatx4*      op = reinterpret_cast<floatx4*>(out + rbase);

    // ---- load; entropy partials; exact s = x/10 + g (Markstein div-by-10); bins; s->LDS ----
    float sZ = 0.f, sZL = 0.f;
#pragma unroll
    for (int q = 0; q < EPT / 4; ++q) {
        float4 xx = xp[(q << 8) + t];
        float4 gg = gp[(q << 8) + t];
        float xa[4] = {xx.x, xx.y, xx.z, xx.w};
        float ga[4] = {gg.x, gg.y, gg.z, gg.w};
        floatx4 so;
        unsigned pk = 0;
#pragma unroll
        for (int jj = 0; jj < 4; ++jj) {
            float xs = xa[jj];
            xv[4 * q + jj] = xs;
            float l = xs * 0.1f;                  // y0 = RN(x * RN(0.1))
            float e = __expf(l);
            sZ  += e;
            sZL = __builtin_fmaf(e, l, sZL);
            // correctly-rounded x/10: q10 = y0 + (x - 10*y0)*0.1 (x/10 never at f32 midpoint)
            float q10 = __builtin_fmaf(__builtin_fmaf(-10.0f, l, xs), 0.1f, l);
            float s = q10 + ga[jj];
            so[jj] = s;
            int b = (int)__builtin_fmaf(s, 16.0f, 64.0f);   // (s+4)*16, monotone in s
            b = min(max(b, 0), 255);
            pk |= (unsigned)b << (8 * jj);
        }
        s4[(q << 8) + t] = so;                    // same-thread spill; no barrier needed
        bp[q] = pk;
    }

    // ---- entropy reduce (m = 0 is safe: |x*0.1| < ~0.6) ----
#pragma unroll
    for (int sft = 32; sft >= 1; sft >>= 1) { sZ += __shfl_xor(sZ, sft); sZL += __shfl_xor(sZL, sft); }
    if (lane == 0) { fred[w] = sZ; fred[4 + w] = sZL; }

    // zero bin histogram (1280 words) + counter
    unsigned* h0 = &hist0[0][0];
#pragma unroll
    for (int i = 0; i < 5; ++i) h0[t + 256 * i] = 0;
    if (t == 0) sh_cnt = 0;
    __syncthreads();                                   // B1

    if (t == 0) {
        float Z = fred[0] + fred[1] + fred[2] + fred[3];
        float L = fred[4] + fred[5] + fred[6] + fred[7];
        float H = __logf(Z) - L / Z;                   // H = lnZ - E[l]
        if (USE_WS) rowH[row] = H;
        else atomicAdd(entAcc, H * invB);
    }

    // ---- value-bin histogram (near-uniform bins; 4-way slot split; 2-way aliasing free) ----
#pragma unroll
    for (int q = 0; q < EPT / 4; ++q) {
        unsigned pk = bp[q];
#pragma unroll
        for (int jj = 0; jj < 4; ++jj)
            atomicAdd(&hist0[(pk >> (8 * jj)) & 255u][lane & 3], 1u);
    }
    __syncthreads();                                   // B2

    // merge slots + inclusive suffix scan (shfl) to find crossing bin B*
    unsigned v = hist0[t][0] + hist0[t][1] + hist0[t][2] + hist0[t][3];
#pragma unroll
    for (int sft = 1; sft < 64; sft <<= 1) {
        unsigned tmp = __shfl(v, lane + sft);
        v += (lane + sft < 64) ? tmp : 0u;
    }
    if (lane == 0) wtot[w] = v;
    unsigned vnext = __shfl(v, lane + 1);
    __syncthreads();                                   // B3
    unsigned Kr = KSEL;
    {
        unsigned hi = 0;
#pragma unroll
        for (int c = 0; c < 4; ++c) hi += (c > w) ? wtot[c] : 0u;
        unsigned cum     = v + hi;                          // # keys with bin >= t
        unsigned cumNext = ((lane < 63) ? vnext : 0u) + hi; // # keys with bin >  t
        if (cum >= Kr && cumNext < Kr) { sh_digit = (unsigned)t; sh_above = cumNext; }
    }
    __syncthreads();                                   // B4
    const unsigned Bstar = sh_digit;
    Kr -= sh_above;       // 1-based rank of threshold within bin B* (from largest)

    // ---- append candidates (bin == B*) to LDS list (s read back same-thread) ----
#pragma unroll
    for (int q = 0; q < EPT / 4; ++q) {
        unsigned pk = bp[q];
#pragma unroll
        for (int jj = 0; jj < 4; ++jj) {
            if (((pk >> (8 * jj)) & 255u) == Bstar) {
                unsigned p = atomicAdd(&sh_cnt, 1u);
                if (p < CAP) list[p] = s_lds[(q << 10) + 4 * t + jj];
            }
        }
    }
    __syncthreads();                                   // B5

    // ---- exact rank among the ~25-95 candidates (float compares) ----
    const unsigned M = sh_cnt;
    for (unsigned i = t; i < M; i += TPB) {
        float ki = list[i];
        unsigned gt = 0, eqc = 0;
        for (unsigned j2 = 0; j2 < M; ++j2) {
            float kj = list[j2];                       // broadcast read
            gt  += (kj > ki)  ? 1u : 0u;
            eqc += (kj == ki) ? 1u : 0u;
        }
        if (gt < Kr && Kr <= gt + eqc) { sh_thr = ki; sh_take = Kr - gt; sh_eq = eqc; }
    }
    __syncthreads();                                   // B6
    const float    thr    = sh_thr;    // exact K-th largest s overall
    const unsigned KrTake = sh_take;   // # equal-to-thr to accept
    const unsigned EqTot  = sh_eq;     // # equal-to-thr total

    if (KrTake == EqTot) {
        // ---- FAST PATH (unique threshold, the ~always case): sel = s >= thr ----
#pragma unroll
        for (int q = 0; q < EPT / 4; ++q) {
            floatx4 sq = s4[(q << 8) + t];
            floatx4 o4;
#pragma unroll
            for (int jj = 0; jj < 4; ++jj)
                o4[jj] = (sq[jj] >= thr) ? xv[4 * q + jj] : 0.0f;
            __builtin_nontemporal_store(o4, &op[(q << 8) + t]);
        }
    } else {
        // ===== degenerate ties: lowest-index-first, column order c = q*1024 + t*4 + jj =====
        unsigned eq[4];
#pragma unroll
        for (int q = 0; q < 4; ++q) {
            floatx4 sq = s4[(q << 8) + t];
            unsigned e = 0;
#pragma unroll
            for (int jj = 0; jj < 4; ++jj) e += (sq[jj] == thr) ? 1u : 0u;
            eq[q] = e;
        }
        unsigned wA = eq[0] | (eq[1] << 16);
        unsigned wB = eq[2] | (eq[3] << 16);
        unsigned sA = wA, sB = wB;
#pragma unroll
        for (int sft = 1; sft < 64; sft <<= 1) {       // inclusive prefix scan within wave
            unsigned ta = __shfl(sA, lane - sft);
            unsigned tb = __shfl(sB, lane - sft);
            if (lane >= sft) { sA += ta; sB += tb; }
        }
        if (lane == 63) { wtA[w] = sA; wtB[w] = sB; }
        __syncthreads();                               // B7 (block-uniform branch: legal)
        unsigned offA = 0, offB = 0, totA = 0, totB = 0;
#pragma unroll
        for (int c = 0; c < 4; ++c) {
            totA += wtA[c]; totB += wtB[c];
            if (c < w) { offA += wtA[c]; offB += wtB[c]; }
        }
        unsigned exA = offA + sA - wA;                 // exclusive prefix, packed halves
        unsigned exB = offB + sB - wB;
        unsigned tot0 = totA & 0xFFFFu, tot1 = totA >> 16, tot2 = totB & 0xFFFFu;
        unsigned baseq[4] = {0u, tot0, tot0 + tot1, tot0 + tot1 + tot2};
        unsigned exq[4]   = {exA & 0xFFFFu, exA >> 16, exB & 0xFFFFu, exB >> 16};

#pragma unroll
        for (int q = 0; q < EPT / 4; ++q) {
            unsigned pos = baseq[q] + exq[q];          // equals before my first elem of this q
            floatx4 sq = s4[(q << 8) + t];
            floatx4 o4;
#pragma unroll
            for (int jj = 0; jj < 4; ++jj) {
                bool sel;
                if (sq[jj] > thr)        sel = true;
                else if (sq[jj] == thr)  { sel = (pos < KrTake); ++pos; }
                else                     sel = false;
                o4[jj] = sel ? xv[4 * q + jj] : 0.0f;
            }
            __builtin_nontemporal_store(o4, &op[(q << 8) + t]);
        }
    }
}

__global__ void skw_zero(float* p) { *p = 0.0f; }

// Deterministic fixed-order mean of rowH -> out scalar.
__global__ void skw_reduce(const float* __restrict__ rowH, float* __restrict__ outp, int B)
{
    __shared__ float red[256];
    int t = threadIdx.x;
    float s = 0.f;
    for (int i = t; i < B; i += 256) s += rowH[i];
    red[t] = s; __syncthreads();
    for (int st = 128; st > 0; st >>= 1) { if (t < st) red[t] += red[t + st]; __syncthreads(); }
    if (t == 0) *outp = red[0] / (float)B;
}

extern "C" void kernel_launch(void* const* d_in, const int* in_sizes, int n_in,
                              void* d_out, int out_size, void* d_ws, size_t ws_size,
                              hipStream_t stream)
{
    const float* x = (const float*)d_in[0];
    const float* g = (const float*)d_in[1];
    float* out = (float*)d_out;
    const int BN = in_sizes[0];
    const int B  = BN / NN;
    float* entp = out + (size_t)BN;

    if (ws_size >= (size_t)B * sizeof(float)) {
        float* rowH = (float*)d_ws;
        skw_main<true><<<B, TPB, 0, stream>>>(x, g, out, rowH, nullptr, 0.f);
        skw_reduce<<<1, 256, 0, stream>>>(rowH, entp, B);
    } else {
        skw_zero<<<1, 1, 0, stream>>>(entp);
        skw_main<false><<<B, TPB, 0, stream>>>(x, g, out, nullptr, entp, 1.0f / (float)B);
    }
}

// Round 14
// 163.281 us; speedup vs baseline: 1.4620x; 1.0126x over previous
//
#include <hip/hip_runtime.h>
#include <math.h>

#define TPB 256
#define EPT 16      // elements per thread
#define NN  4096    // row length (fixed by problem)
#define KSEL 410    // K = round(4096 * 0.1)
#define CAP 1024    // candidate list capacity (expected max bin ~95)

typedef float floatx4 __attribute__((ext_vector_type(4)));

// Async global->LDS DMA, 16B/lane. LDS dest is wave-uniform base (HW adds lane*16),
// global src is per-lane [m104/m108]. Issue position is preserved by the compiler
// (void side-effecting intrinsic) — the ONLY load form that provably stays in flight.
__device__ __forceinline__ void dma16(const float* gsrc, float* lds) {
    __builtin_amdgcn_global_load_lds(
        (__attribute__((address_space(1))) void*)(void*)gsrc,
        (__attribute__((address_space(3))) void*)(void*)lds,
        16, 0, 0);
}

template <bool USE_WS>
__global__ __launch_bounds__(TPB)
void skw_main(const float* __restrict__ x, const float* __restrict__ g,
              float* __restrict__ out, float* __restrict__ rowH,
              float* __restrict__ entAcc, float invB)
{
    const int row  = blockIdx.x;
    const int t    = threadIdx.x;
    const int w    = t >> 6;          // wave id 0..3
    const int lane = t & 63;
    const size_t rbase = (size_t)row * NN;

    unsigned bp[EPT / 4];             // value-domain bins, byte-packed

    __shared__ float    stage[2 * NN];   // 32 KB: x in [0,4096), g->s in [4096,8192)
    __shared__ unsigned hist0[256][5];   // bin histogram: 4 slots + 1 pad (stride 5)
    __shared__ unsigned wtot[4];
    __shared__ unsigned wtA[4], wtB[4];
    __shared__ float    fred[8];
    __shared__ unsigned sh_digit, sh_above, sh_cnt, sh_take, sh_eq;
    __shared__ float    sh_thr;

    float*   list = reinterpret_cast<float*>(&hist0[0][0]);  // alias; used after B4 (5120B >= CAP*4)
    floatx4* sx4  = reinterpret_cast<floatx4*>(stage);           // x region, float4 view
    floatx4* ss4  = reinterpret_cast<floatx4*>(stage + NN);      // g/s region, float4 view

    const float* xr = x + rbase;
    const float* gr = g + rbase;
    floatx4*     op = reinterpret_cast<floatx4*>(out + rbase);

    // ---- stage x,g via async DMA: wave w stages EXACTLY the chunks it consumes ----
    // chunk c = q*4 + w holds flat floats [c*256, c*256+256); thread t=(w,lane) consumes
    // flat q*1024 + t*4 = c*256 + lane*4. All deps same-wave => NO barrier, no dbuf.
#pragma unroll
    for (int q = 0; q < 4; ++q) {
        const int c = (q << 2) + w;
        dma16(xr + (c << 8) + (lane << 2), &stage[c << 8]);
        dma16(gr + (c << 8) + (lane << 2), &stage[NN + (c << 8)]);
    }

    // zero bin histogram (+ counter) while DMA is in flight
    unsigned* h0 = &hist0[0][0];
#pragma unroll
    for (int i = 0; i < 5; ++i) h0[t + 256 * i] = 0;
    if (t == 0) sh_cnt = 0;

    // wait for my wave's 8 DMAs (the only outstanding vmem)
    asm volatile("s_waitcnt vmcnt(0)" ::: "memory");

    // ---- keys/bins/entropy from LDS; s = x/10 + g exact (Markstein); s overwrites g ----
    float sZ = 0.f, sZL = 0.f;
#pragma unroll
    for (int q = 0; q < EPT / 4; ++q) {
        floatx4 xx = sx4[(q << 8) + t];
        floatx4 gg = ss4[(q << 8) + t];
        floatx4 so;
        unsigned pk = 0;
#pragma unroll
        for (int jj = 0; jj < 4; ++jj) {
            float xs = xx[jj];
            float l = xs * 0.1f;                  // y0 = RN(x * RN(0.1))
            float e = __expf(l);
            sZ  += e;
            sZL = __builtin_fmaf(e, l, sZL);
            // correctly-rounded x/10: q10 = y0 + (x - 10*y0)*0.1 (x/10 never at f32 midpoint)
            float q10 = __builtin_fmaf(__builtin_fmaf(-10.0f, l, xs), 0.1f, l);
            float s = q10 + gg[jj];
            so[jj] = s;
            int b = (int)__builtin_fmaf(s, 16.0f, 64.0f);   // (s+4)*16, monotone in s
            b = min(max(b, 0), 255);
            pk |= (unsigned)b << (8 * jj);
        }
        ss4[(q << 8) + t] = so;                   // same-thread overwrite; no barrier
        bp[q] = pk;
    }

    // ---- entropy reduce (m = 0 is safe: |x*0.1| < ~0.6) ----
#pragma unroll
    for (int sft = 32; sft >= 1; sft >>= 1) { sZ += __shfl_xor(sZ, sft); sZL += __shfl_xor(sZL, sft); }
    if (lane == 0) { fred[w] = sZ; fred[4 + w] = sZL; }
    __syncthreads();                                   // B1

    if (t == 0) {
        float Z = fred[0] + fred[1] + fred[2] + fred[3];
        float L = fred[4] + fred[5] + fred[6] + fred[7];
        float H = __logf(Z) - L / Z;                   // H = lnZ - E[l]
        if (USE_WS) rowH[row] = H;
        else atomicAdd(entAcc, H * invB);
    }

    // ---- value-bin histogram (near-uniform bins; 4-way slot split; 2-way aliasing free) ----
#pragma unroll
    for (int q = 0; q < EPT / 4; ++q) {
        unsigned pk = bp[q];
#pragma unroll
        for (int jj = 0; jj < 4; ++jj)
            atomicAdd(&hist0[(pk >> (8 * jj)) & 255u][lane & 3], 1u);
    }
    __syncthreads();                                   // B2

    // merge slots + inclusive suffix scan (shfl) to find crossing bin B*
    unsigned v = hist0[t][0] + hist0[t][1] + hist0[t][2] + hist0[t][3];
#pragma unroll
    for (int sft = 1; sft < 64; sft <<= 1) {
        unsigned tmp = __shfl(v, lane + sft);
        v += (lane + sft < 64) ? tmp : 0u;
    }
    if (lane == 0) wtot[w] = v;
    unsigned vnext = __shfl(v, lane + 1);
    __syncthreads();                                   // B3
    unsigned Kr = KSEL;
    {
        unsigned hi = 0;
#pragma unroll
        for (int c = 0; c < 4; ++c) hi += (c > w) ? wtot[c] : 0u;
        unsigned cum     = v + hi;                          // # keys with bin >= t
        unsigned cumNext = ((lane < 63) ? vnext : 0u) + hi; // # keys with bin >  t
        if (cum >= Kr && cumNext < Kr) { sh_digit = (unsigned)t; sh_above = cumNext; }
    }
    __syncthreads();                                   // B4
    const unsigned Bstar = sh_digit;
    Kr -= sh_above;       // 1-based rank of threshold within bin B* (from largest)

    // ---- append candidates (bin == B*) to LDS list (s read back same-thread) ----
#pragma unroll
    for (int q = 0; q < EPT / 4; ++q) {
        unsigned pk = bp[q];
#pragma unroll
        for (int jj = 0; jj < 4; ++jj) {
            if (((pk >> (8 * jj)) & 255u) == Bstar) {
                unsigned p = atomicAdd(&sh_cnt, 1u);
                if (p < CAP) list[p] = stage[NN + (q << 10) + 4 * t + jj];
            }
        }
    }
    __syncthreads();                                   // B5

    // ---- exact rank among the ~25-95 candidates (float compares) ----
    const unsigned M = sh_cnt;
    for (unsigned i = t; i < M; i += TPB) {
        float ki = list[i];
        unsigned gt = 0, eqc = 0;
        for (unsigned j2 = 0; j2 < M; ++j2) {
            float kj = list[j2];                       // broadcast read
            gt  += (kj > ki)  ? 1u : 0u;
            eqc += (kj == ki) ? 1u : 0u;
        }
        if (gt < Kr && Kr <= gt + eqc) { sh_thr = ki; sh_take = Kr - gt; sh_eq = eqc; }
    }
    __syncthreads();                                   // B6
    const float    thr    = sh_thr;    // exact K-th largest s overall
    const unsigned KrTake = sh_take;   // # equal-to-thr to accept
    const unsigned EqTot  = sh_eq;     // # equal-to-thr total

    if (KrTake == EqTot) {
        // ---- FAST PATH (unique threshold, the ~always case): sel = s >= thr ----
#pragma unroll
        for (int q = 0; q < EPT / 4; ++q) {
            floatx4 sq = ss4[(q << 8) + t];
            floatx4 xq = sx4[(q << 8) + t];
            floatx4 o4;
#pragma unroll
            for (int jj = 0; jj < 4; ++jj)
                o4[jj] = (sq[jj] >= thr) ? xq[jj] : 0.0f;
            __builtin_nontemporal_store(o4, &op[(q << 8) + t]);
        }
    } else {
        // ===== degenerate ties: lowest-index-first, column order c = q*1024 + t*4 + jj =====
        unsigned eq[4];
#pragma unroll
        for (int q = 0; q < 4; ++q) {
            floatx4 sq = ss4[(q << 8) + t];
            unsigned e = 0;
#pragma unroll
            for (int jj = 0; jj < 4; ++jj) e += (sq[jj] == thr) ? 1u : 0u;
            eq[q] = e;
        }
        unsigned wA = eq[0] | (eq[1] << 16);
        unsigned wB = eq[2] | (eq[3] << 16);
        unsigned sA = wA, sB = wB;
#pragma unroll
        for (int sft = 1; sft < 64; sft <<= 1) {       // inclusive prefix scan within wave
            unsigned ta = __shfl(sA, lane - sft);
            unsigned tb = __shfl(sB, lane - sft);
            if (lane >= sft) { sA += ta; sB += tb; }
        }
        if (lane == 63) { wtA[w] = sA; wtB[w] = sB; }
        __syncthreads();                               // B7 (block-uniform branch: legal)
        unsigned offA = 0, offB = 0, totA = 0, totB = 0;
#pragma unroll
        for (int c = 0; c < 4; ++c) {
            totA += wtA[c]; totB += wtB[c];
            if (c < w) { offA += wtA[c]; offB += wtB[c]; }
        }
        unsigned exA = offA + sA - wA;                 // exclusive prefix, packed halves
        unsigned exB = offB + sB - wB;
        unsigned tot0 = totA & 0xFFFFu, tot1 = totA >> 16, tot2 = totB & 0xFFFFu;
        unsigned baseq[4] = {0u, tot0, tot0 + tot1, tot0 + tot1 + tot2};
        unsigned exq[4]   = {exA & 0xFFFFu, exA >> 16, exB & 0xFFFFu, exB >> 16};

#pragma unroll
        for (int q = 0; q < EPT / 4; ++q) {
            unsigned pos = baseq[q] + exq[q];          // equals before my first elem of this q
            floatx4 sq = ss4[(q << 8) + t];
            floatx4 xq = sx4[(q << 8) + t];
            floatx4 o4;
#pragma unroll
            for (int jj = 0; jj < 4; ++jj) {
                bool sel;
                if (sq[jj] > thr)        sel = true;
                else if (sq[jj] == thr)  { sel = (pos < KrTake); ++pos; }
                else                     sel = false;
                o4[jj] = sel ? xq[jj] : 0.0f;
            }
            __builtin_nontemporal_store(o4, &op[(q << 8) + t]);
        }
    }
}

__global__ void skw_zero(float* p) { *p = 0.0f; }

// Deterministic fixed-order mean of rowH -> out scalar.
__global__ void skw_reduce(const float* __restrict__ rowH, float* __restrict__ outp, int B)
{
    __shared__ float red[256];
    int t = threadIdx.x;
    float s = 0.f;
    for (int i = t; i < B; i += 256) s += rowH[i];
    red[t] = s; __syncthreads();
    for (int st = 128; st > 0; st >>= 1) { if (t < st) red[t] += red[t + st]; __syncthreads(); }
    if (t == 0) *outp = red[0] / (float)B;
}

extern "C" void kernel_launch(void* const* d_in, const int* in_sizes, int n_in,
                              void* d_out, int out_size, void* d_ws, size_t ws_size,
                              hipStream_t stream)
{
    const float* x = (const float*)d_in[0];
    const float* g = (const float*)d_in[1];
    float* out = (float*)d_out;
    const int BN = in_sizes[0];
    const int B  = BN / NN;
    float* entp = out + (size_t)BN;

    if (ws_size >= (size_t)B * sizeof(float)) {
        float* rowH = (float*)d_ws;
        skw_main<true><<<B, TPB, 0, stream>>>(x, g, out, rowH, nullptr, 0.f);
        skw_reduce<<<1, 256, 0, stream>>>(rowH, entp, B);
    } else {
        skw_zero<<<1, 1, 0, stream>>>(entp);
        skw_main<false><<<B, TPB, 0, stream>>>(x, g, out, nullptr, entp, 1.0f / (float)B);
    }
}